// Round 12
// baseline (258.615 us; speedup 1.0000x reference)
//
#include <hip/hip_runtime.h>

typedef __bf16 bf16;
typedef __bf16 bf16x4 __attribute__((ext_vector_type(4)));
typedef __bf16 bf16x8 __attribute__((ext_vector_type(8)));
typedef float  f32x4  __attribute__((ext_vector_type(4)));

#define MFMA16(a, b, c) __builtin_amdgcn_mfma_f32_16x16x32_bf16((a), (b), (c), 0, 0, 0)

// async global->LDS, 16B per lane; LDS dest = wave-uniform base + lane*16
__device__ __forceinline__ void async_copy16(const void* g, void* l) {
  __builtin_amdgcn_global_load_lds(
      (const __attribute__((address_space(1))) unsigned int*)g,
      (__attribute__((address_space(3))) unsigned int*)l, 16, 0, 0);
}

// ------------------------------------------------- fused f32->bf16 (5 segments)
struct CvtArgs {
  const float* src[5];
  bf16* dst[5];
  int blk_start[6];
};
__global__ void k_cvt_all(CvtArgs a) {
  int b = blockIdx.x;
  int seg = 0;
#pragma unroll
  for (int s = 1; s < 5; ++s) seg += (b >= a.blk_start[s]);
  int i = (b - a.blk_start[seg]) * 1024 + threadIdx.x * 4;
  float4 v = *(const float4*)(a.src[seg] + i);
  bf16x4 o = { (bf16)v.x, (bf16)v.y, (bf16)v.z, (bf16)v.w };
  *(bf16x4*)(a.dst[seg] + i) = o;
}

// ------------------------------------------- 128x128-tile GEMM body, BK=64
// C[m][n] = sum_k A[m][k]*B[n][k] (A MxK, B NxK row-major bf16 => A@B^T).
// Two independent 32-column LDS stages per iter; 8 async copies then ONE
// barrier pair per 64 of K. LDS 32 KB/block.
template <int OUTF32>
__device__ __forceinline__ void gemm128_body(
    const bf16* __restrict__ A, const bf16* __restrict__ B, void* __restrict__ Cp,
    const float* __restrict__ bias, int m0, int n0, int N, int K) {
  __shared__ alignas(16) bf16 As[2][128 * 32];
  __shared__ alignas(16) bf16 Bs[2][128 * 32];
  const int tid = threadIdx.x;
  const int lane = tid & 63;
  const int w = tid >> 6;
  const int quad = lane >> 4;
  const int l16 = lane & 15;
  const int wr = (w >> 1) * 64;
  const int wc = (w & 1) * 64;

  // staging: flat [row][k32], row = tid/4 (+64 second copy), k = (tid%4)*8
  const int srow = tid >> 2;
  const int skk = (tid & 3) * 8;
  const bf16* Ag = A + (long)(m0 + srow) * K + skk;
  const bf16* Bg = B + (long)(n0 + srow) * K + skk;
  const long half = 64L * K;
  bf16* AsW0 = As[0] + w * 512;  // wave-uniform LDS bases (lane*16B added by HW)
  bf16* BsW0 = Bs[0] + w * 512;
  bf16* AsW1 = As[1] + w * 512;
  bf16* BsW1 = Bs[1] + w * 512;

  f32x4 acc[4][4];
#pragma unroll
  for (int i = 0; i < 4; ++i)
#pragma unroll
    for (int j = 0; j < 4; ++j) acc[i][j] = (f32x4){0.f, 0.f, 0.f, 0.f};

  for (int k0 = 0; k0 < K; k0 += 64) {
    async_copy16(Ag + k0, AsW0);
    async_copy16(Ag + half + k0, AsW0 + 2048);
    async_copy16(Bg + k0, BsW0);
    async_copy16(Bg + half + k0, BsW0 + 2048);
    async_copy16(Ag + k0 + 32, AsW1);
    async_copy16(Ag + half + k0 + 32, AsW1 + 2048);
    async_copy16(Bg + k0 + 32, BsW1);
    async_copy16(Bg + half + k0 + 32, BsW1 + 2048);
    __syncthreads();
#pragma unroll
    for (int p = 0; p < 2; ++p) {
      const bf16* AsP = As[p];
      const bf16* BsP = Bs[p];
      bf16x8 af[4], bfr[4];
#pragma unroll
      for (int i = 0; i < 4; ++i)
        af[i] = *(const bf16x8*)&AsP[(wr + i * 16 + l16) * 32 + quad * 8];
#pragma unroll
      for (int j = 0; j < 4; ++j)
        bfr[j] = *(const bf16x8*)&BsP[(wc + j * 16 + l16) * 32 + quad * 8];
#pragma unroll
      for (int i = 0; i < 4; ++i)
#pragma unroll
        for (int j = 0; j < 4; ++j) acc[i][j] = MFMA16(af[i], bfr[j], acc[i][j]);
    }
    __syncthreads();
  }

#pragma unroll
  for (int i = 0; i < 4; ++i)
#pragma unroll
    for (int j = 0; j < 4; ++j)
#pragma unroll
      for (int r = 0; r < 4; ++r) {
        long row = m0 + wr + i * 16 + quad * 4 + r;
        int col = n0 + wc + j * 16 + l16;
        if (OUTF32)
          ((float*)Cp)[row * N + col] = acc[i][j][r] + bias[col];
        else
          ((bf16*)Cp)[row * N + col] = (bf16)acc[i][j][r];
      }
}

// Combined QK-projection (bid<1024) + V^T (bid>=1024), SINGLE body call.
// launch_bounds(256,3): capacity 3 blocks/CU = 768 -> grid 1536 = exactly
// TWO full cohorts (zero tail) vs 4/CU's 1.5 cohorts; per-CU throughput at
// 3 ~= at 4 (R10 vs R11: 2 us apart), so tail elimination should net a win.
// Index maps keep the LARGE operand (xb) XCD-local: same-tile readers 64
// block-ids apart (64 % 8 == 0 under round-robin dispatch).
__global__ __launch_bounds__(256, 3) void k_gemm_qkv(
    const bf16* __restrict__ xb, const bf16* __restrict__ Wqk, bf16* __restrict__ QKb,
    const bf16* __restrict__ Wvb, bf16* __restrict__ VtG) {
  int bid = blockIdx.x;
  const bf16 *A, *B;
  bf16* C;
  int m0, n0, N;
  if (bid < 1024) {
    A = xb; B = Wqk; C = QKb;
    m0 = (bid & 63) * 128; n0 = (bid >> 6) * 128; N = 2048;
  } else {
    int id = bid - 1024;
    A = Wvb; B = xb; C = VtG;
    m0 = (id >> 6) * 128; n0 = (id & 63) * 128; N = 8192;
  }
  gemm128_body<0>(A, B, C, nullptr, m0, n0, N, 1024);
}

__global__ __launch_bounds__(256, 4) void k_gemm_out(
    const bf16* __restrict__ Ab, const bf16* __restrict__ Wub, float* __restrict__ out,
    const float* __restrict__ bu) {
  gemm128_body<1>(Ab, Wub, out, bu, blockIdx.x * 128, blockIdx.y * 128, 1024, 1024);
}

// --------------------------------------------------------- flash attention
// Byte-exact R9/R10/R11 body (91-93 us, VGPR 124, no spill): R5 inner loop +
// XCD grid. __expf kept: exp2 variant flipped the allocator into spill
// (R7/R8). This kernel sits on an allocator cliff at VGPR~124; do not perturb.
__global__ __launch_bounds__(256, 2) void k_attn(
    const bf16* __restrict__ Q, const bf16* __restrict__ Kb,
    const bf16* __restrict__ Vt, bf16* __restrict__ O) {
  __shared__ alignas(16) bf16 Ps[256][72];  // Q staging, then P[qrow][kv]; wave-private rows
  __shared__ alignas(16) bf16 Ks[64][72];   // K tile [kv][d]
  __shared__ alignas(16) bf16 Vs[64][72];   // V^T tile [d][kv]

  const int tid = threadIdx.x;
  const int lane = tid & 63;
  const int w = tid >> 6;
  const int quad = lane >> 4;
  const int l16 = lane & 15;
  const int bh = blockIdx.x;   // 0..63 (fast dim -> XCD = bh & 7)
  const int qt = blockIdx.y;   // 0..7 (256-row q tiles)
  const int bb = bh >> 4;
  const int h = bh & 15;
  const int hoff = h * 64;
  const long rowQ0 = (long)bb * 2048 + qt * 256;
  const long kv0 = (long)bb * 2048;

  // ---- stage Q (row = tid; wave w stages its own rows), pre-scaled by 1/8
  {
    const bf16* p = Q + (rowQ0 + tid) * 2048 + hoff;
#pragma unroll
    for (int u = 0; u < 8; ++u) {
      bf16x8 v = *(const bf16x8*)(p + u * 8);
      bf16x8 o;
#pragma unroll
      for (int j = 0; j < 8; ++j) o[j] = (bf16)((float)v[j] * 0.125f);
      *(bf16x8*)&Ps[tid][u * 8] = o;
    }
  }
  // no barrier: staging + frag reads wave-private; DS in-order per wave
  bf16x8 bq[4][2];  // B-frag of Q: B[k=d][n=qrow]
#pragma unroll
  for (int g = 0; g < 4; ++g)
#pragma unroll
    for (int ss = 0; ss < 2; ++ss)
      bq[g][ss] = *(const bf16x8*)&Ps[w * 64 + g * 16 + l16][ss * 32 + quad * 8];

  f32x4 accO[4][4];
  float lp[4] = {0.f, 0.f, 0.f, 0.f};
#pragma unroll
  for (int g = 0; g < 4; ++g)
#pragma unroll
    for (int t = 0; t < 4; ++t) accO[g][t] = (f32x4){0.f, 0.f, 0.f, 0.f};

  const int srow = tid >> 2;
  const int scol = (tid & 3) * 8;
  const bf16* kp = Kb + (kv0 + srow) * 2048 + hoff + scol;
  const bf16* vp = Vt + (long)(hoff + srow) * 8192 + kv0 + scol;

  // prefetch tile 0 into registers
  bf16x8 kr0 = *(const bf16x8*)kp;
  bf16x8 kr1 = *(const bf16x8*)(kp + 32);
  bf16x8 vr0 = *(const bf16x8*)vp;
  bf16x8 vr1 = *(const bf16x8*)(vp + 32);

  for (int kt = 0; kt < 32; ++kt) {
    __syncthreads();  // prior iter's Ks/Vs reads complete
    *(bf16x8*)&Ks[srow][scol] = kr0;
    *(bf16x8*)&Ks[srow][scol + 32] = kr1;
    *(bf16x8*)&Vs[srow][scol] = vr0;
    *(bf16x8*)&Vs[srow][scol + 32] = vr1;
    __syncthreads();
    if (kt < 31) {  // prefetch next tile; latency overlaps compute phase
      const bf16* kp2 = kp + (long)(kt + 1) * 64 * 2048;
      const bf16* vp2 = vp + (kt + 1) * 64;
      kr0 = *(const bf16x8*)kp2;
      kr1 = *(const bf16x8*)(kp2 + 32);
      vr0 = *(const bf16x8*)vp2;
      vr1 = *(const bf16x8*)(vp2 + 32);
    }

    // hoist K A-frags and V B-frags (shared across all 4 q-groups)
    bf16x8 ak[4][2], bv[2][4];
#pragma unroll
    for (int mt = 0; mt < 4; ++mt) {
      ak[mt][0] = *(const bf16x8*)&Ks[mt * 16 + l16][quad * 8];
      ak[mt][1] = *(const bf16x8*)&Ks[mt * 16 + l16][32 + quad * 8];
    }
#pragma unroll
    for (int ss = 0; ss < 2; ++ss)
#pragma unroll
      for (int t = 0; t < 4; ++t)
        bv[ss][t] = *(const bf16x8*)&Vs[t * 16 + l16][ss * 32 + quad * 8];

#pragma unroll
    for (int g = 0; g < 4; ++g) {
      // S^T[kv][qrow] = K Q^T for this q-group
      f32x4 st[4];
#pragma unroll
      for (int mt = 0; mt < 4; ++mt) {
        st[mt] = (f32x4){0.f, 0.f, 0.f, 0.f};
        st[mt] = MFMA16(ak[mt][0], bq[g][0], st[mt]);
        st[mt] = MFMA16(ak[mt][1], bq[g][1], st[mt]);
      }
      // max-free softmax: per-lane row sums (lane col l16 = qrow fixed);
      // 4 consecutive kv per lane -> b64 P write
#pragma unroll
      for (int mt = 0; mt < 4; ++mt) {
        bf16x4 pk;
#pragma unroll
        for (int r = 0; r < 4; ++r) {
          float pv = __expf(st[mt][r]);
          lp[g] += pv;
          pk[r] = (bf16)pv;
        }
        *(bf16x4*)&Ps[w * 64 + g * 16 + l16][mt * 16 + quad * 4] = pk;
      }
      // O += P V (Ps rows wave-private; DS in-order per wave)
#pragma unroll
      for (int ss = 0; ss < 2; ++ss) {
        bf16x8 ap = *(const bf16x8*)&Ps[w * 64 + g * 16 + l16][ss * 32 + quad * 8];
#pragma unroll
        for (int t = 0; t < 4; ++t)
          accO[g][t] = MFMA16(ap, bv[ss][t], accO[g][t]);
      }
    }
  }

  // reduce row-sums across quads (lane col l16 = qrow), then epilogue
#pragma unroll
  for (int g = 0; g < 4; ++g) {
    float l = lp[g];
    l += __shfl_xor(l, 16);
    l += __shfl_xor(l, 32);
    float linv = 1.f / l;
#pragma unroll
    for (int r = 0; r < 4; ++r) {
      float inv = __shfl(linv, (lane & 48) | (quad * 4 + r));
      long row = rowQ0 + w * 64 + g * 16 + quad * 4 + r;
#pragma unroll
      for (int t = 0; t < 4; ++t)
        O[row * 1024 + hoff + t * 16 + l16] = (bf16)(accO[g][t][r] * inv);
    }
  }
}

// ----------------------------------------------------------------- launch
extern "C" void kernel_launch(void* const* d_in, const int* in_sizes, int n_in,
                              void* d_out, int out_size, void* d_ws, size_t ws_size,
                              hipStream_t stream) {
  const float* x  = (const float*)d_in[0];
  const float* Wk = (const float*)d_in[1];
  const float* Wq = (const float*)d_in[2];
  const float* Wv = (const float*)d_in[3];
  const float* Wu = (const float*)d_in[4];
  const float* bu = (const float*)d_in[5];
  float* out = (float*)d_out;

  const int XE = 4 * 2048 * 1024;  // 8388608
  const int WE = 1024 * 1024;      // 1048576

  bf16* p = (bf16*)d_ws;
  bf16* xb   = p; p += XE;
  bf16* Wqkb = p; p += 2 * WE;  // Wq rows | Wk rows
  bf16* Wvb  = p; p += WE;
  bf16* Wub  = p; p += WE;
  bf16* QKb  = p; p += 2 * XE;  // [8192][2048]: Q | K
  bf16* VtG  = p; p += XE;      // V^T [1024][8192]
  bf16* Ab   = p; p += XE;      // attention output [8192][1024]

  CvtArgs ca;
  ca.src[0] = x;  ca.dst[0] = xb;
  ca.src[1] = Wq; ca.dst[1] = Wqkb;
  ca.src[2] = Wk; ca.dst[2] = Wqkb + WE;
  ca.src[3] = Wv; ca.dst[3] = Wvb;
  ca.src[4] = Wu; ca.dst[4] = Wub;
  ca.blk_start[0] = 0;
  ca.blk_start[1] = XE / 1024;
  ca.blk_start[2] = ca.blk_start[1] + WE / 1024;
  ca.blk_start[3] = ca.blk_start[2] + WE / 1024;
  ca.blk_start[4] = ca.blk_start[3] + WE / 1024;
  ca.blk_start[5] = ca.blk_start[4] + WE / 1024;
  k_cvt_all<<<ca.blk_start[5], 256, 0, stream>>>(ca);

  k_gemm_qkv<<<1536, 256, 0, stream>>>(xb, Wqkb, QKb, Wvb, VtG);

  // grid: bh fast (XCD-aligned K/V reuse), qt slow
  k_attn<<<dim3(64, 8), 256, 0, stream>>>(QKb, QKb + 1024, VtG, Ab);

  k_gemm_out<<<dim3(64, 8), 256, 0, stream>>>(Ab, Wub, out, bu);
}

// Round 13
// 252.380 us; speedup vs baseline: 1.0247x; 1.0247x over previous
//
#include <hip/hip_runtime.h>

typedef __bf16 bf16;
typedef __bf16 bf16x4 __attribute__((ext_vector_type(4)));
typedef __bf16 bf16x8 __attribute__((ext_vector_type(8)));
typedef float  f32x4  __attribute__((ext_vector_type(4)));

#define MFMA16(a, b, c) __builtin_amdgcn_mfma_f32_16x16x32_bf16((a), (b), (c), 0, 0, 0)

// async global->LDS, 16B per lane; LDS dest = wave-uniform base + lane*16
__device__ __forceinline__ void async_copy16(const void* g, void* l) {
  __builtin_amdgcn_global_load_lds(
      (const __attribute__((address_space(1))) unsigned int*)g,
      (__attribute__((address_space(3))) unsigned int*)l, 16, 0, 0);
}

// ------------------------------------------------- fused f32->bf16 (5 segments)
// 8 elems/thread: two float4 loads in flight -> better MLP on the HBM-bound
// conversion; grid halves to 6144 blocks.
struct CvtArgs {
  const float* src[5];
  bf16* dst[5];
  int blk_start[6];
};
__global__ void k_cvt_all(CvtArgs a) {
  int b = blockIdx.x;
  int seg = 0;
#pragma unroll
  for (int s = 1; s < 5; ++s) seg += (b >= a.blk_start[s]);
  int i = (b - a.blk_start[seg]) * 2048 + threadIdx.x * 8;
  float4 v0 = *(const float4*)(a.src[seg] + i);
  float4 v1 = *(const float4*)(a.src[seg] + i + 4);
  bf16x8 o = { (bf16)v0.x, (bf16)v0.y, (bf16)v0.z, (bf16)v0.w,
               (bf16)v1.x, (bf16)v1.y, (bf16)v1.z, (bf16)v1.w };
  *(bf16x8*)(a.dst[seg] + i) = o;
}

// ------------------------------------------- 128x128-tile GEMM body, BK=64
// C[m][n] = sum_k A[m][k]*B[n][k] (A MxK, B NxK row-major bf16 => A@B^T).
// Two independent 32-column LDS stages per iter; 8 async copies then ONE
// barrier pair per 64 of K. LDS 32 KB/block.
template <int OUTF32>
__device__ __forceinline__ void gemm128_body(
    const bf16* __restrict__ A, const bf16* __restrict__ B, void* __restrict__ Cp,
    const float* __restrict__ bias, int m0, int n0, int N, int K) {
  __shared__ alignas(16) bf16 As[2][128 * 32];
  __shared__ alignas(16) bf16 Bs[2][128 * 32];
  const int tid = threadIdx.x;
  const int lane = tid & 63;
  const int w = tid >> 6;
  const int quad = lane >> 4;
  const int l16 = lane & 15;
  const int wr = (w >> 1) * 64;
  const int wc = (w & 1) * 64;

  // staging: flat [row][k32], row = tid/4 (+64 second copy), k = (tid%4)*8
  const int srow = tid >> 2;
  const int skk = (tid & 3) * 8;
  const bf16* Ag = A + (long)(m0 + srow) * K + skk;
  const bf16* Bg = B + (long)(n0 + srow) * K + skk;
  const long half = 64L * K;
  bf16* AsW0 = As[0] + w * 512;  // wave-uniform LDS bases (lane*16B added by HW)
  bf16* BsW0 = Bs[0] + w * 512;
  bf16* AsW1 = As[1] + w * 512;
  bf16* BsW1 = Bs[1] + w * 512;

  f32x4 acc[4][4];
#pragma unroll
  for (int i = 0; i < 4; ++i)
#pragma unroll
    for (int j = 0; j < 4; ++j) acc[i][j] = (f32x4){0.f, 0.f, 0.f, 0.f};

  for (int k0 = 0; k0 < K; k0 += 64) {
    async_copy16(Ag + k0, AsW0);
    async_copy16(Ag + half + k0, AsW0 + 2048);
    async_copy16(Bg + k0, BsW0);
    async_copy16(Bg + half + k0, BsW0 + 2048);
    async_copy16(Ag + k0 + 32, AsW1);
    async_copy16(Ag + half + k0 + 32, AsW1 + 2048);
    async_copy16(Bg + k0 + 32, BsW1);
    async_copy16(Bg + half + k0 + 32, BsW1 + 2048);
    __syncthreads();
#pragma unroll
    for (int p = 0; p < 2; ++p) {
      const bf16* AsP = As[p];
      const bf16* BsP = Bs[p];
      bf16x8 af[4], bfr[4];
#pragma unroll
      for (int i = 0; i < 4; ++i)
        af[i] = *(const bf16x8*)&AsP[(wr + i * 16 + l16) * 32 + quad * 8];
#pragma unroll
      for (int j = 0; j < 4; ++j)
        bfr[j] = *(const bf16x8*)&BsP[(wc + j * 16 + l16) * 32 + quad * 8];
#pragma unroll
      for (int i = 0; i < 4; ++i)
#pragma unroll
        for (int j = 0; j < 4; ++j) acc[i][j] = MFMA16(af[i], bfr[j], acc[i][j]);
    }
    __syncthreads();
  }

#pragma unroll
  for (int i = 0; i < 4; ++i)
#pragma unroll
    for (int j = 0; j < 4; ++j)
#pragma unroll
      for (int r = 0; r < 4; ++r) {
        long row = m0 + wr + i * 16 + quad * 4 + r;
        int col = n0 + wc + j * 16 + l16;
        if (OUTF32)
          ((float*)Cp)[row * N + col] = acc[i][j][r] + bias[col];
        else
          ((bf16*)Cp)[row * N + col] = (bf16)acc[i][j][r];
      }
}

// Combined QK-projection (bid<1024) + V^T (bid>=1024), SINGLE body call.
// launch_bounds(256,4): best measured (R11). R12's (256,3) cohort theory
// regressed 3.4 us — per-CU throughput at 3 blocks < tail savings.
// Index maps keep the LARGE operand (xb) XCD-local: same-tile readers 64
// block-ids apart (64 % 8 == 0 under round-robin dispatch).
__global__ __launch_bounds__(256, 4) void k_gemm_qkv(
    const bf16* __restrict__ xb, const bf16* __restrict__ Wqk, bf16* __restrict__ QKb,
    const bf16* __restrict__ Wvb, bf16* __restrict__ VtG) {
  int bid = blockIdx.x;
  const bf16 *A, *B;
  bf16* C;
  int m0, n0, N;
  if (bid < 1024) {
    A = xb; B = Wqk; C = QKb;
    m0 = (bid & 63) * 128; n0 = (bid >> 6) * 128; N = 2048;
  } else {
    int id = bid - 1024;
    A = Wvb; B = xb; C = VtG;
    m0 = (id >> 6) * 128; n0 = (id & 63) * 128; N = 8192;
  }
  gemm128_body<0>(A, B, C, nullptr, m0, n0, N, 1024);
}

__global__ __launch_bounds__(256, 4) void k_gemm_out(
    const bf16* __restrict__ Ab, const bf16* __restrict__ Wub, float* __restrict__ out,
    const float* __restrict__ bu) {
  gemm128_body<1>(Ab, Wub, out, bu, blockIdx.x * 128, blockIdx.y * 128, 1024, 1024);
}

// --------------------------------------------------------- flash attention
// Byte-exact R9-R12 body (91-93 us, VGPR 124, no spill): R5 inner loop +
// XCD grid. __expf kept: exp2 variant flipped the allocator into spill
// (R7/R8). This kernel sits on an allocator cliff at VGPR~124; do not perturb.
__global__ __launch_bounds__(256, 2) void k_attn(
    const bf16* __restrict__ Q, const bf16* __restrict__ Kb,
    const bf16* __restrict__ Vt, bf16* __restrict__ O) {
  __shared__ alignas(16) bf16 Ps[256][72];  // Q staging, then P[qrow][kv]; wave-private rows
  __shared__ alignas(16) bf16 Ks[64][72];   // K tile [kv][d]
  __shared__ alignas(16) bf16 Vs[64][72];   // V^T tile [d][kv]

  const int tid = threadIdx.x;
  const int lane = tid & 63;
  const int w = tid >> 6;
  const int quad = lane >> 4;
  const int l16 = lane & 15;
  const int bh = blockIdx.x;   // 0..63 (fast dim -> XCD = bh & 7)
  const int qt = blockIdx.y;   // 0..7 (256-row q tiles)
  const int bb = bh >> 4;
  const int h = bh & 15;
  const int hoff = h * 64;
  const long rowQ0 = (long)bb * 2048 + qt * 256;
  const long kv0 = (long)bb * 2048;

  // ---- stage Q (row = tid; wave w stages its own rows), pre-scaled by 1/8
  {
    const bf16* p = Q + (rowQ0 + tid) * 2048 + hoff;
#pragma unroll
    for (int u = 0; u < 8; ++u) {
      bf16x8 v = *(const bf16x8*)(p + u * 8);
      bf16x8 o;
#pragma unroll
      for (int j = 0; j < 8; ++j) o[j] = (bf16)((float)v[j] * 0.125f);
      *(bf16x8*)&Ps[tid][u * 8] = o;
    }
  }
  // no barrier: staging + frag reads wave-private; DS in-order per wave
  bf16x8 bq[4][2];  // B-frag of Q: B[k=d][n=qrow]
#pragma unroll
  for (int g = 0; g < 4; ++g)
#pragma unroll
    for (int ss = 0; ss < 2; ++ss)
      bq[g][ss] = *(const bf16x8*)&Ps[w * 64 + g * 16 + l16][ss * 32 + quad * 8];

  f32x4 accO[4][4];
  float lp[4] = {0.f, 0.f, 0.f, 0.f};
#pragma unroll
  for (int g = 0; g < 4; ++g)
#pragma unroll
    for (int t = 0; t < 4; ++t) accO[g][t] = (f32x4){0.f, 0.f, 0.f, 0.f};

  const int srow = tid >> 2;
  const int scol = (tid & 3) * 8;
  const bf16* kp = Kb + (kv0 + srow) * 2048 + hoff + scol;
  const bf16* vp = Vt + (long)(hoff + srow) * 8192 + kv0 + scol;

  // prefetch tile 0 into registers
  bf16x8 kr0 = *(const bf16x8*)kp;
  bf16x8 kr1 = *(const bf16x8*)(kp + 32);
  bf16x8 vr0 = *(const bf16x8*)vp;
  bf16x8 vr1 = *(const bf16x8*)(vp + 32);

  for (int kt = 0; kt < 32; ++kt) {
    __syncthreads();  // prior iter's Ks/Vs reads complete
    *(bf16x8*)&Ks[srow][scol] = kr0;
    *(bf16x8*)&Ks[srow][scol + 32] = kr1;
    *(bf16x8*)&Vs[srow][scol] = vr0;
    *(bf16x8*)&Vs[srow][scol + 32] = vr1;
    __syncthreads();
    if (kt < 31) {  // prefetch next tile; latency overlaps compute phase
      const bf16* kp2 = kp + (long)(kt + 1) * 64 * 2048;
      const bf16* vp2 = vp + (kt + 1) * 64;
      kr0 = *(const bf16x8*)kp2;
      kr1 = *(const bf16x8*)(kp2 + 32);
      vr0 = *(const bf16x8*)vp2;
      vr1 = *(const bf16x8*)(vp2 + 32);
    }

    // hoist K A-frags and V B-frags (shared across all 4 q-groups)
    bf16x8 ak[4][2], bv[2][4];
#pragma unroll
    for (int mt = 0; mt < 4; ++mt) {
      ak[mt][0] = *(const bf16x8*)&Ks[mt * 16 + l16][quad * 8];
      ak[mt][1] = *(const bf16x8*)&Ks[mt * 16 + l16][32 + quad * 8];
    }
#pragma unroll
    for (int ss = 0; ss < 2; ++ss)
#pragma unroll
      for (int t = 0; t < 4; ++t)
        bv[ss][t] = *(const bf16x8*)&Vs[t * 16 + l16][ss * 32 + quad * 8];

#pragma unroll
    for (int g = 0; g < 4; ++g) {
      // S^T[kv][qrow] = K Q^T for this q-group
      f32x4 st[4];
#pragma unroll
      for (int mt = 0; mt < 4; ++mt) {
        st[mt] = (f32x4){0.f, 0.f, 0.f, 0.f};
        st[mt] = MFMA16(ak[mt][0], bq[g][0], st[mt]);
        st[mt] = MFMA16(ak[mt][1], bq[g][1], st[mt]);
      }
      // max-free softmax: per-lane row sums (lane col l16 = qrow fixed);
      // 4 consecutive kv per lane -> b64 P write
#pragma unroll
      for (int mt = 0; mt < 4; ++mt) {
        bf16x4 pk;
#pragma unroll
        for (int r = 0; r < 4; ++r) {
          float pv = __expf(st[mt][r]);
          lp[g] += pv;
          pk[r] = (bf16)pv;
        }
        *(bf16x4*)&Ps[w * 64 + g * 16 + l16][mt * 16 + quad * 4] = pk;
      }
      // O += P V (Ps rows wave-private; DS in-order per wave)
#pragma unroll
      for (int ss = 0; ss < 2; ++ss) {
        bf16x8 ap = *(const bf16x8*)&Ps[w * 64 + g * 16 + l16][ss * 32 + quad * 8];
#pragma unroll
        for (int t = 0; t < 4; ++t)
          accO[g][t] = MFMA16(ap, bv[ss][t], accO[g][t]);
      }
    }
  }

  // reduce row-sums across quads (lane col l16 = qrow), then epilogue
#pragma unroll
  for (int g = 0; g < 4; ++g) {
    float l = lp[g];
    l += __shfl_xor(l, 16);
    l += __shfl_xor(l, 32);
    float linv = 1.f / l;
#pragma unroll
    for (int r = 0; r < 4; ++r) {
      float inv = __shfl(linv, (lane & 48) | (quad * 4 + r));
      long row = rowQ0 + w * 64 + g * 16 + quad * 4 + r;
#pragma unroll
      for (int t = 0; t < 4; ++t)
        O[row * 1024 + hoff + t * 16 + l16] = (bf16)(accO[g][t][r] * inv);
    }
  }
}

// ----------------------------------------------------------------- launch
extern "C" void kernel_launch(void* const* d_in, const int* in_sizes, int n_in,
                              void* d_out, int out_size, void* d_ws, size_t ws_size,
                              hipStream_t stream) {
  const float* x  = (const float*)d_in[0];
  const float* Wk = (const float*)d_in[1];
  const float* Wq = (const float*)d_in[2];
  const float* Wv = (const float*)d_in[3];
  const float* Wu = (const float*)d_in[4];
  const float* bu = (const float*)d_in[5];
  float* out = (float*)d_out;

  const int XE = 4 * 2048 * 1024;  // 8388608
  const int WE = 1024 * 1024;      // 1048576

  bf16* p = (bf16*)d_ws;
  bf16* xb   = p; p += XE;
  bf16* Wqkb = p; p += 2 * WE;  // Wq rows | Wk rows
  bf16* Wvb  = p; p += WE;
  bf16* Wub  = p; p += WE;
  bf16* QKb  = p; p += 2 * XE;  // [8192][2048]: Q | K
  bf16* VtG  = p; p += XE;      // V^T [1024][8192]
  bf16* Ab   = p; p += XE;      // attention output [8192][1024]

  CvtArgs ca;
  ca.src[0] = x;  ca.dst[0] = xb;
  ca.src[1] = Wq; ca.dst[1] = Wqkb;
  ca.src[2] = Wk; ca.dst[2] = Wqkb + WE;
  ca.src[3] = Wv; ca.dst[3] = Wvb;
  ca.src[4] = Wu; ca.dst[4] = Wub;
  ca.blk_start[0] = 0;
  ca.blk_start[1] = XE / 2048;                 // 4096
  ca.blk_start[2] = ca.blk_start[1] + WE / 2048;
  ca.blk_start[3] = ca.blk_start[2] + WE / 2048;
  ca.blk_start[4] = ca.blk_start[3] + WE / 2048;
  ca.blk_start[5] = ca.blk_start[4] + WE / 2048;  // 6144 total
  k_cvt_all<<<ca.blk_start[5], 256, 0, stream>>>(ca);

  k_gemm_qkv<<<1536, 256, 0, stream>>>(xb, Wqkb, QKb, Wvb, VtG);

  // grid: bh fast (XCD-aligned K/V reuse), qt slow
  k_attn<<<dim3(64, 8), 256, 0, stream>>>(QKb, QKb + 1024, VtG, Ab);

  k_gemm_out<<<dim3(64, 8), 256, 0, stream>>>(Ab, Wub, out, bu);
}